// Round 12
// baseline (168.772 us; speedup 1.0000x reference)
//
#include <hip/hip_runtime.h>
#include <hip/hip_fp16.h>

#define D_FEAT 128

typedef _Float16 half8_t __attribute__((ext_vector_type(8)));
typedef float float4_t __attribute__((ext_vector_type(4)));

__device__ __forceinline__ float h16_to_f(unsigned short u) {
    union { unsigned short u; _Float16 f; } cv; cv.u = u; return (float)cv.f;
}
__device__ __forceinline__ unsigned short f_to_h16(float f) {
    union { unsigned short u; _Float16 f; } cv; cv.f = (_Float16)f; return cv.u;
}

// ============================================================================
// Stage 1 (fused, role by blockIdx): input fp32->fp16 | W^T fp16 | zero
// sedge4 slack | per-(block,bucket) histogram partials (plain stores,
// ZERO global atomics, no memset prerequisite).
// ============================================================================
__global__ __launch_bounds__(256) void prep_kernel(
    const float* __restrict__ input, unsigned* __restrict__ inph_u2,
    const float* __restrict__ W, __half* __restrict__ wt16,
    unsigned* __restrict__ sedge4_slack,
    const int* __restrict__ erow, int* __restrict__ part,
    int nconv4, int n_edges, int convBlocks, int wBlocks)
{
    __shared__ int lh[256];
    const int bid = blockIdx.x;
    const int t = threadIdx.x;

    if (bid < convBlocks) {
        int tid = bid * 256 + t;
        if (tid < nconv4) {
            float4 v = reinterpret_cast<const float4*>(input)[tid];
            __half2 a = __floats2half2_rn(v.x, v.y);
            __half2 b = __floats2half2_rn(v.z, v.w);
            uint2 p;
            p.x = *reinterpret_cast<unsigned*>(&a);
            p.y = *reinterpret_cast<unsigned*>(&b);
            reinterpret_cast<uint2*>(inph_u2)[tid] = p;
        }
    } else if (bid < convBlocks + wBlocks) {
        int idx = (bid - convBlocks) * 256 + t;
        if (idx < D_FEAT * D_FEAT) {
            int n = idx >> 7, k = idx & 127;
            wt16[n * D_FEAT + k] = __float2half(W[k * D_FEAT + n]);
        }
    } else if (bid == convBlocks + wBlocks) {
        if (t < 16) sedge4_slack[t] = 0u;
    } else {
        // bucket histogram partials: 4096 edges per block
        int hb = bid - convBlocks - wBlocks - 1;
        lh[t] = 0;
        __syncthreads();
        int base = hb * 4096;
        int end = base + 4096; if (end > n_edges) end = n_edges;
        for (int i = base + t; i < end; i += 256)
            atomicAdd(&lh[erow[i] >> 8], 1);
        __syncthreads();
        part[hb * 256 + t] = lh[t];
    }
}

// ============================================================================
// Stage 2 (single block): column-scan part[hb][t] -> absolute
// per-(block,bucket) bases, + bucket exclusive scan -> bbase.
// ============================================================================
__global__ __launch_bounds__(256) void pscan_kernel(
    int* __restrict__ part, int* __restrict__ bbase,
    int nb, int histBlocks, int n_edges)
{
    __shared__ int lds[256];
    const int t = threadIdx.x;
    int run = 0;
    for (int hb = 0; hb < histBlocks; ++hb) {
        int v = part[hb * 256 + t];
        part[hb * 256 + t] = run;
        run += v;
    }
    int tot = run;               // total edges in bucket t
    lds[t] = tot;
    __syncthreads();
#pragma unroll
    for (int off = 1; off < 256; off <<= 1) {
        int add = (t >= off) ? lds[t - off] : 0;
        __syncthreads();
        lds[t] += add;
        __syncthreads();
    }
    int ex = lds[t] - tot;       // exclusive bucket base
    if (t <= nb) {
        // bbase[t] for t<nb; bbase[nb]=n_edges handled below (ex==n_edges there)
        bbase[t] = (t < nb) ? ex : n_edges;
    }
    // lift partials to absolute bases
    for (int hb = 0; hb < histBlocks; ++hb)
        part[hb * 256 + t] += ex;
}

// ============================================================================
// Stage 3a: bin edges into bucket runs. LDS cursors start at precomputed
// absolute per-(block,bucket) bases -> zero global atomics, single pass.
// ============================================================================
__global__ __launch_bounds__(256) void bin_kernel(
    const int* __restrict__ erow, const int* __restrict__ ecol,
    const float* __restrict__ ew, const int* __restrict__ part,
    uint2* __restrict__ btmp, int n_edges)
{
    __shared__ int lcnt[256];
    const int t = threadIdx.x;
    const int base = blockIdx.x * 4096;
    lcnt[t] = part[blockIdx.x * 256 + t];
    __syncthreads();
    int end = base + 4096; if (end > n_edges) end = n_edges;
    for (int i = base + t; i < end; i += 256) {
        int r = erow[i];
        int pos = atomicAdd(&lcnt[r >> 8], 1);
        uint2 p;
        p.x = ((unsigned)r << 16) | (unsigned)ecol[i];
        p.y = __float_as_uint(ew[i]);
        btmp[pos] = p;
    }
}

// ============================================================================
// Stage 3b: per-bucket CSR build + final scatter (R11-proven).
// ============================================================================
__global__ __launch_bounds__(256) void sort_kernel(
    const uint2* __restrict__ btmp, const int* __restrict__ bbase,
    int* __restrict__ cnt, int* __restrict__ beg,
    unsigned* __restrict__ sedge4, int n)
{
    __shared__ int lscan[256];
    __shared__ int lofs[256];
    const int b = blockIdx.x;
    const int t = threadIdx.x;
    const int lo = bbase[b];
    const int hi = bbase[b + 1];

    lscan[t] = 0;
    __syncthreads();
    for (int i = lo + t; i < hi; i += 256) {
        int rl = (btmp[i].x >> 16) & 255;
        atomicAdd(&lscan[rl], 1);
    }
    __syncthreads();
    int v = lscan[t];
    __syncthreads();
#pragma unroll
    for (int off = 1; off < 256; off <<= 1) {
        int add = (t >= off) ? lscan[t - off] : 0;
        __syncthreads();
        lscan[t] += add;
        __syncthreads();
    }
    int ex = lscan[t] - v;
    lofs[t] = ex;
    int row = b * 256 + t;
    if (row < n) {
        cnt[row] = v;
        beg[row] = lo + ex;
    }
    __syncthreads();
    for (int i = lo + t; i < hi; i += 256) {
        uint2 p = btmp[i];
        int rl = (p.x >> 16) & 255;
        int pos = atomicAdd(&lofs[rl], 1);
        float w = __uint_as_float(p.y);
        sedge4[lo + pos] = (p.x & 0xFFFFu) | ((unsigned)f_to_h16(w) << 16);
    }
}

// ============================================================================
// Stage 4: CSR SpMM, 4B records, fp16 gather. Predicated full-MLP groups of
// 16 (16 independent gathers in flight; record array has zeroed slack).
// ============================================================================
__global__ __launch_bounds__(256) void spmm4_kernel(
    const __half2* __restrict__ inph, const float* __restrict__ h0,
    const int* __restrict__ begp, const int* __restrict__ cnt,
    const unsigned* __restrict__ sedge4,
    const float* __restrict__ alpha_p, __half2* __restrict__ s16out, int n)
{
    int lane = threadIdx.x & 63;
    int row  = blockIdx.x * 4 + (threadIdx.x >> 6);
    if (row >= n) return;

    int deg = cnt[row];
    int beg = begp[row];

    float2 a0 = {0.f, 0.f}, a1 = {0.f, 0.f}, a2 = {0.f, 0.f}, a3 = {0.f, 0.f};
    for (int e = 0; e < deg; e += 16) {
        unsigned r[16];
#pragma unroll
        for (int i = 0; i < 16; ++i) r[i] = sedge4[beg + e + i];
        __half2 v[16];
#pragma unroll
        for (int i = 0; i < 16; ++i)
            v[i] = inph[(size_t)(r[i] & 0xFFFFu) * 64 + lane];
#pragma unroll
        for (int i = 0; i < 16; ++i) {
            float w = h16_to_f((e + i < deg) ? (unsigned short)(r[i] >> 16)
                                             : (unsigned short)0);
            float2 f = __half22float2(v[i]);
            if ((i & 3) == 0) { a0.x = fmaf(w, f.x, a0.x); a0.y = fmaf(w, f.y, a0.y); }
            if ((i & 3) == 1) { a1.x = fmaf(w, f.x, a1.x); a1.y = fmaf(w, f.y, a1.y); }
            if ((i & 3) == 2) { a2.x = fmaf(w, f.x, a2.x); a2.y = fmaf(w, f.y, a2.y); }
            if ((i & 3) == 3) { a3.x = fmaf(w, f.x, a3.x); a3.y = fmaf(w, f.y, a3.y); }
        }
    }
    float2 acc;
    acc.x = (a0.x + a1.x) + (a2.x + a3.x);
    acc.y = (a0.y + a1.y) + (a2.y + a3.y);

    const float alpha = alpha_p[0];
    const float oma   = 1.0f - alpha;
    float2 h = reinterpret_cast<const float2*>(h0)[(size_t)row * 64 + lane];
    float sx = fmaf(oma, acc.x, alpha * h.x);
    float sy = fmaf(oma, acc.y, alpha * h.y);
    s16out[(size_t)row * 64 + lane] = __floats2half2_rn(sx, sy);
}

// ============================================================================
// Stage 5: MFMA GEMM + blend + residual (R6-verified layout).
// ============================================================================
__global__ __launch_bounds__(256) void gemm_mfma_kernel(
    const __half* __restrict__ s16, const __half* __restrict__ wt16,
    const float* __restrict__ input, float* __restrict__ out,
    const float* __restrict__ lamda_p, const int* __restrict__ l_p,
    int n_rows)
{
    const int wave = threadIdx.x >> 6;
    const int lane = threadIdx.x & 63;
    const int row0 = (blockIdx.x * 4 + wave) * 16;
    if (row0 >= n_rows) return;

    const int mr = lane & 15;
    const int kg = lane >> 4;

    const _Float16* sp = reinterpret_cast<const _Float16*>(s16);
    const _Float16* wp = reinterpret_cast<const _Float16*>(wt16);

    float4_t acc[8];
#pragma unroll
    for (int nt = 0; nt < 8; ++nt) acc[nt] = (float4_t){0.f, 0.f, 0.f, 0.f};

#pragma unroll
    for (int ks = 0; ks < 4; ++ks) {
        const int kofs = ks * 32 + kg * 8;
        half8_t a = *reinterpret_cast<const half8_t*>(
            sp + (size_t)(row0 + mr) * D_FEAT + kofs);
#pragma unroll
        for (int nt = 0; nt < 8; ++nt) {
            half8_t b = *reinterpret_cast<const half8_t*>(
                wp + (size_t)(nt * 16 + mr) * D_FEAT + kofs);
            acc[nt] = __builtin_amdgcn_mfma_f32_16x16x32_f16(a, b, acc[nt], 0, 0, 0);
        }
    }

    const float lamda = lamda_p[0];
    const float theta = fminf(1.0f, logf(lamda / (float)l_p[0] + 1.0f));
    const float om_theta = 1.0f - theta;

#pragma unroll
    for (int nt = 0; nt < 8; ++nt) {
#pragma unroll
        for (int r = 0; r < 4; ++r) {
            const int row = row0 + kg * 4 + r;
            const int col = nt * 16 + mr;
            const size_t idx = (size_t)row * D_FEAT + col;
            const float s = (float)sp[idx];
            out[idx] = fmaf(theta, acc[nt][r], fmaf(om_theta, s, input[idx]));
        }
    }
}

// ======================= fallback paths (B/C, from R5) ======================
__global__ __launch_bounds__(256) void hist_kernel(
    const int* __restrict__ erow, int* __restrict__ cnt, int n_edges)
{
    int e = blockIdx.x * 256 + threadIdx.x;
    if (e < n_edges) atomicAdd(&cnt[erow[e]], 1);
}

__global__ __launch_bounds__(256) void prep_noW_kernel(
    const float* __restrict__ input, unsigned* __restrict__ inph_u2,
    const int* __restrict__ erow, int* __restrict__ cnt,
    int nconv4, int n_edges)
{
    int tid = blockIdx.x * 256 + threadIdx.x;
    if (tid < nconv4) {
        float4 v = reinterpret_cast<const float4*>(input)[tid];
        __half2 a = __floats2half2_rn(v.x, v.y);
        __half2 b = __floats2half2_rn(v.z, v.w);
        uint2 p;
        p.x = *reinterpret_cast<unsigned*>(&a);
        p.y = *reinterpret_cast<unsigned*>(&b);
        reinterpret_cast<uint2*>(inph_u2)[tid] = p;
    } else {
        int e = tid - nconv4;
        if (e < n_edges) atomicAdd(&cnt[erow[e]], 1);
    }
}

__global__ __launch_bounds__(256) void partial_kernel(
    const int* __restrict__ cnt, int* __restrict__ partial, int n)
{
    __shared__ int lds[4];
    int i = blockIdx.x * 256 + threadIdx.x;
    int v = (i < n) ? cnt[i] : 0;
#pragma unroll
    for (int off = 32; off > 0; off >>= 1) v += __shfl_down(v, off, 64);
    if ((threadIdx.x & 63) == 0) lds[threadIdx.x >> 6] = v;
    __syncthreads();
    if (threadIdx.x == 0)
        partial[blockIdx.x] = lds[0] + lds[1] + lds[2] + lds[3];
}

__global__ __launch_bounds__(256) void scan_partial_kernel(
    int* __restrict__ partial, int nb)
{
    __shared__ int lds[256];
    int t = threadIdx.x;
    int v = (t < nb) ? partial[t] : 0;
    lds[t] = v;
    __syncthreads();
#pragma unroll
    for (int off = 1; off < 256; off <<= 1) {
        int add = (t >= off) ? lds[t - off] : 0;
        __syncthreads();
        lds[t] += add;
        __syncthreads();
    }
    if (t < nb) partial[t] = lds[t] - v;
}

__global__ __launch_bounds__(256) void scan_final_kernel(
    const int* __restrict__ cnt, const int* __restrict__ partial,
    int* __restrict__ cursor, int n)
{
    __shared__ int lds[256];
    int t = threadIdx.x;
    int i = blockIdx.x * 256 + t;
    int v = (i < n) ? cnt[i] : 0;
    lds[t] = v;
    __syncthreads();
#pragma unroll
    for (int off = 1; off < 256; off <<= 1) {
        int add = (t >= off) ? lds[t - off] : 0;
        __syncthreads();
        lds[t] += add;
        __syncthreads();
    }
    if (i < n) cursor[i] = lds[t] - v + partial[blockIdx.x];
}

__global__ __launch_bounds__(256) void edge_scatter_kernel(
    const int* __restrict__ erow, const int* __restrict__ ecol,
    const float* __restrict__ ew, int* __restrict__ cursor,
    uint2* __restrict__ sedge, int n_edges)
{
    int e = blockIdx.x * 256 + threadIdx.x;
    if (e >= n_edges) return;
    int r = erow[e];
    int pos = atomicAdd(&cursor[r], 1);
    uint2 p;
    p.x = (unsigned)ecol[e];
    p.y = __float_as_uint(ew[e]);
    sedge[pos] = p;
}

__global__ __launch_bounds__(256) void spmm_fp16_kernel(
    const __half2* __restrict__ inph, const float* __restrict__ h0,
    const int* __restrict__ cursor, const int* __restrict__ cnt,
    const uint2* __restrict__ sedge,
    const float* __restrict__ alpha_p, float* __restrict__ outp, int n)
{
    int lane = threadIdx.x & 63;
    int row  = blockIdx.x * 4 + (threadIdx.x >> 6);
    if (row >= n) return;
    int deg = cnt[row];
    int beg = cursor[row] - deg;
    float2 accA = make_float2(0.f, 0.f), accB = make_float2(0.f, 0.f);
    int e = 0;
    for (; e + 2 <= deg; e += 2) {
        uint2 e0 = sedge[beg + e], e1 = sedge[beg + e + 1];
        __half2 v0 = inph[(size_t)e0.x * 64 + lane];
        __half2 v1 = inph[(size_t)e1.x * 64 + lane];
        float w0 = __uint_as_float(e0.y), w1 = __uint_as_float(e1.y);
        float2 f0 = __half22float2(v0), f1 = __half22float2(v1);
        accA.x = fmaf(w0, f0.x, accA.x); accA.y = fmaf(w0, f0.y, accA.y);
        accB.x = fmaf(w1, f1.x, accB.x); accB.y = fmaf(w1, f1.y, accB.y);
    }
    if (e < deg) {
        uint2 e0 = sedge[beg + e];
        __half2 v0 = inph[(size_t)e0.x * 64 + lane];
        float w0 = __uint_as_float(e0.y);
        float2 f0 = __half22float2(v0);
        accA.x = fmaf(w0, f0.x, accA.x); accA.y = fmaf(w0, f0.y, accA.y);
    }
    float2 acc; acc.x = accA.x + accB.x; acc.y = accA.y + accB.y;
    const float alpha = alpha_p[0], oma = 1.0f - alpha;
    float2 h = reinterpret_cast<const float2*>(h0)[(size_t)row * 64 + lane];
    float2 s;
    s.x = fmaf(oma, acc.x, alpha * h.x);
    s.y = fmaf(oma, acc.y, alpha * h.y);
    reinterpret_cast<float2*>(outp)[(size_t)row * 64 + lane] = s;
}

__global__ __launch_bounds__(256) void spmm_fp32_kernel(
    const float* __restrict__ input, const float* __restrict__ h0,
    const int* __restrict__ cursor, const int* __restrict__ cnt,
    const uint2* __restrict__ sedge,
    const float* __restrict__ alpha_p, float* __restrict__ outp, int n)
{
    int lane = threadIdx.x & 63;
    int row  = blockIdx.x * 4 + (threadIdx.x >> 6);
    if (row >= n) return;
    int deg = cnt[row];
    int beg = cursor[row] - deg;
    const float2* in2 = reinterpret_cast<const float2*>(input);
    float2 acc = make_float2(0.f, 0.f);
    for (int e = 0; e < deg; ++e) {
        uint2 ed = sedge[beg + e];
        float w = __uint_as_float(ed.y);
        float2 v = in2[(size_t)ed.x * 64 + lane];
        acc.x = fmaf(w, v.x, acc.x);
        acc.y = fmaf(w, v.y, acc.y);
    }
    const float alpha = alpha_p[0], oma = 1.0f - alpha;
    float2 h = reinterpret_cast<const float2*>(h0)[(size_t)row * 64 + lane];
    float2 s;
    s.x = fmaf(oma, acc.x, alpha * h.x);
    s.y = fmaf(oma, acc.y, alpha * h.y);
    reinterpret_cast<float2*>(outp)[(size_t)row * 64 + lane] = s;
}

__global__ __launch_bounds__(256) void fused_kernel(
    float* __restrict__ io, const float* __restrict__ input,
    const float* __restrict__ W,
    const float* __restrict__ lamda_p, const int* __restrict__ l_p,
    int n_rows)
{
    __shared__ float s_lds[2][D_FEAT];
    const int j = threadIdx.x & 127;
    const int r = threadIdx.x >> 7;
    float wcol[D_FEAT];
#pragma unroll
    for (int k = 0; k < D_FEAT; ++k) wcol[k] = W[k * D_FEAT + j];
    const float lamda = lamda_p[0];
    const float theta = fminf(1.0f, logf(lamda / (float)l_p[0] + 1.0f));
    const float om_theta = 1.0f - theta;
    for (int row0 = blockIdx.x * 2; row0 < n_rows; row0 += gridDim.x * 2) {
        const int row = row0 + r;
        const bool active = row < n_rows;
        float sj = 0.0f;
        if (active) {
            sj = io[(size_t)row * D_FEAT + j];
            s_lds[r][j] = sj;
        }
        __syncthreads();
        if (active) {
            float dot = 0.0f;
            const float4* s4 = reinterpret_cast<const float4*>(s_lds[r]);
#pragma unroll
            for (int k4 = 0; k4 < D_FEAT / 4; ++k4) {
                const float4 sv = s4[k4];
                dot = fmaf(sv.x, wcol[4 * k4 + 0], dot);
                dot = fmaf(sv.y, wcol[4 * k4 + 1], dot);
                dot = fmaf(sv.z, wcol[4 * k4 + 2], dot);
                dot = fmaf(sv.w, wcol[4 * k4 + 3], dot);
            }
            const size_t base = (size_t)row * D_FEAT + j;
            io[base] = fmaf(theta, dot, om_theta * sj) + input[base];
        }
        __syncthreads();
    }
}

extern "C" void kernel_launch(void* const* d_in, const int* in_sizes, int n_in,
                              void* d_out, int out_size, void* d_ws, size_t ws_size,
                              hipStream_t stream)
{
    const float* input = (const float*)d_in[0];
    const float* h0    = (const float*)d_in[1];
    const float* W     = (const float*)d_in[2];
    const int*   erow  = (const int*)d_in[3];
    const int*   ecol  = (const int*)d_in[4];
    const float* ew    = (const float*)d_in[5];
    const float* lamda = (const float*)d_in[6];
    const float* alpha = (const float*)d_in[7];
    const int*   l_p   = (const int*)d_in[8];
    float* out = (float*)d_out;

    const int n_nodes = in_sizes[0] / D_FEAT;   // 50000
    const int n_edges = in_sizes[3];            // 800000
    const int nb = (n_nodes + 255) / 256;       // 196
    const int nconv4 = n_nodes * D_FEAT / 4;
    const int histBlocks = (n_edges + 4095) / 4096;

    // ---- new-path workspace layout ----
    // cnt:N | beg:N | bbase:257 | part:histBlocks*256 |
    // sedge4:(E+16) u32 | inph:N*128 fp16 | union[btmp E uint2 / s16] | wt16
    char* p = (char*)d_ws;
    auto align16 = [](char* q) {
        return (char*)(((uintptr_t)q + 15) & ~(uintptr_t)15);
    };
    int* cnt      = (int*)p;                    p += (size_t)n_nodes * 4;
    int* beg      = (int*)p;                    p += (size_t)n_nodes * 4;
    int* bbase    = (int*)p;                    p += 257 * 4;
    int* part     = (int*)p;                    p += (size_t)histBlocks * 256 * 4;
    p = align16(p);
    unsigned* sedge4 = (unsigned*)p;            p += ((size_t)n_edges + 16) * 4;
    p = align16(p);
    unsigned* inph  = (unsigned*)p;             p += (size_t)n_nodes * D_FEAT * 2;
    p = align16(p);
    char* unionp = p;
    uint2*  btmp = (uint2*)unionp;
    __half* s16  = (__half*)unionp;
    size_t union_bytes = (size_t)n_nodes * D_FEAT * 2;
    if ((size_t)n_edges * 8 > union_bytes) union_bytes = (size_t)n_edges * 8;
    p += union_bytes;
    p = align16(p);
    __half* wt16 = (__half*)p;                  p += (size_t)D_FEAT * D_FEAT * 2;
    const size_t need_new = (size_t)(p - (char*)d_ws);

    const bool use_new = (ws_size >= need_new) && (n_nodes < 65536) && (nb <= 256);

    if (use_new) {
        const int convBlocks = (nconv4 + 255) / 256;
        const int wBlocks = (D_FEAT * D_FEAT + 255) / 256;
        const int totalBlocks = convBlocks + wBlocks + 1 + histBlocks;

        prep_kernel<<<totalBlocks, 256, 0, stream>>>(
            input, inph, W, wt16, sedge4 + n_edges, erow, part,
            nconv4, n_edges, convBlocks, wBlocks);
        pscan_kernel<<<1, 256, 0, stream>>>(
            part, bbase, nb, histBlocks, n_edges);
        bin_kernel<<<histBlocks, 256, 0, stream>>>(
            erow, ecol, ew, part, btmp, n_edges);
        sort_kernel<<<nb, 256, 0, stream>>>(
            btmp, bbase, cnt, beg, sedge4, n_nodes);
        spmm4_kernel<<<(n_nodes + 3) / 4, 256, 0, stream>>>(
            (const __half2*)inph, h0, beg, cnt, sedge4, alpha,
            (__half2*)s16, n_nodes);
        const int ntiles = (n_nodes + 15) / 16;
        gemm_mfma_kernel<<<(ntiles + 3) / 4, 256, 0, stream>>>(
            s16, wt16, input, out, lamda, l_p, n_nodes);
        return;
    }

    // ---------------- fallback (R5 layout & paths) ----------------
    int*   fcnt     = (int*)d_ws;
    int*   fcursor  = fcnt + n_nodes;
    int*   fpartial = fcursor + n_nodes;
    uint2* fsedge   = (uint2*)(fpartial + 256);
    unsigned* finph = (unsigned*)(fsedge + n_edges);

    const size_t need_base = (size_t)(2 * n_nodes + 256) * 4 + (size_t)n_edges * 8;
    const size_t need_fp16 = need_base + (size_t)n_nodes * D_FEAT * 2;
    const bool use_fp16 = ws_size >= need_fp16;

    hipMemsetAsync(fcnt, 0, (size_t)n_nodes * sizeof(int), stream);

    if (use_fp16) {
        int total = nconv4 + n_edges;
        prep_noW_kernel<<<(total + 255) / 256, 256, 0, stream>>>(
            input, finph, erow, fcnt, nconv4, n_edges);
    } else {
        hist_kernel<<<(n_edges + 255) / 256, 256, 0, stream>>>(erow, fcnt, n_edges);
    }
    partial_kernel<<<nb, 256, 0, stream>>>(fcnt, fpartial, n_nodes);
    scan_partial_kernel<<<1, 256, 0, stream>>>(fpartial, nb);
    scan_final_kernel<<<nb, 256, 0, stream>>>(fcnt, fpartial, fcursor, n_nodes);
    edge_scatter_kernel<<<(n_edges + 255) / 256, 256, 0, stream>>>(
        erow, ecol, ew, fcursor, fsedge, n_edges);
    if (use_fp16) {
        spmm_fp16_kernel<<<(n_nodes + 3) / 4, 256, 0, stream>>>(
            (const __half2*)finph, h0, fcursor, fcnt, fsedge, alpha, out, n_nodes);
    } else {
        spmm_fp32_kernel<<<(n_nodes + 3) / 4, 256, 0, stream>>>(
            input, h0, fcursor, fcnt, fsedge, alpha, out, n_nodes);
    }
    fused_kernel<<<2048, 256, 0, stream>>>(out, input, W, lamda, l_p, n_nodes);
}

// Round 13
// 118.116 us; speedup vs baseline: 1.4289x; 1.4289x over previous
//
#include <hip/hip_runtime.h>
#include <hip/hip_fp16.h>

#define D_FEAT 128

typedef _Float16 half8_t __attribute__((ext_vector_type(8)));
typedef float float4_t __attribute__((ext_vector_type(4)));

__device__ __forceinline__ float h16_to_f(unsigned short u) {
    union { unsigned short u; _Float16 f; } cv; cv.u = u; return (float)cv.f;
}
__device__ __forceinline__ unsigned short f_to_h16(float f) {
    union { unsigned short u; _Float16 f; } cv; cv.f = (_Float16)f; return cv.u;
}

// ============================================================================
// Stage 1 (fused, role by blockIdx): input fp32->fp16 | W^T fp16 | zero
// sedge4 slack | BUCKET histogram (LDS-privatized -> 256 global atomics per
// 4096-edge block). R11-proven.
// ============================================================================
__global__ __launch_bounds__(256) void prep_kernel(
    const float* __restrict__ input, unsigned* __restrict__ inph_u2,
    const float* __restrict__ W, __half* __restrict__ wt16,
    unsigned* __restrict__ sedge4_slack,
    const int* __restrict__ erow, int* __restrict__ bucket_cnt,
    int nconv4, int n_edges, int convBlocks, int wBlocks)
{
    __shared__ int lh[256];
    const int bid = blockIdx.x;
    const int t = threadIdx.x;

    if (bid < convBlocks) {
        int tid = bid * 256 + t;
        if (tid < nconv4) {
            float4 v = reinterpret_cast<const float4*>(input)[tid];
            __half2 a = __floats2half2_rn(v.x, v.y);
            __half2 b = __floats2half2_rn(v.z, v.w);
            uint2 p;
            p.x = *reinterpret_cast<unsigned*>(&a);
            p.y = *reinterpret_cast<unsigned*>(&b);
            reinterpret_cast<uint2*>(inph_u2)[tid] = p;
        }
    } else if (bid < convBlocks + wBlocks) {
        int idx = (bid - convBlocks) * 256 + t;
        if (idx < D_FEAT * D_FEAT) {
            int n = idx >> 7, k = idx & 127;
            wt16[n * D_FEAT + k] = __float2half(W[k * D_FEAT + n]);
        }
    } else if (bid == convBlocks + wBlocks) {
        if (t < 16) sedge4_slack[t] = 0u;
    } else {
        // bucket histogram: 4096 edges per block
        int hb = bid - convBlocks - wBlocks - 1;
        lh[t] = 0;
        __syncthreads();
        int base = hb * 4096;
        int end = base + 4096; if (end > n_edges) end = n_edges;
        for (int i = base + t; i < end; i += 256)
            atomicAdd(&lh[erow[i] >> 8], 1);
        __syncthreads();
        int c = lh[t];
        if (c > 0) atomicAdd(&bucket_cnt[t], c);
    }
}

// ============================================================================
// Stage 2: exclusive scan of <=256 bucket counts (single block, O(256) work
// ONLY — R12's serial-196-loop pscan was a 62us disaster).
// ============================================================================
__global__ __launch_bounds__(256) void bucket_scan_kernel(
    const int* __restrict__ bucket_cnt, int* __restrict__ bcursor,
    int* __restrict__ bbase, int nb, int n_edges)
{
    __shared__ int lds[256];
    int t = threadIdx.x;
    int v = (t < nb) ? bucket_cnt[t] : 0;
    lds[t] = v;
    __syncthreads();
#pragma unroll
    for (int off = 1; off < 256; off <<= 1) {
        int add = (t >= off) ? lds[t - off] : 0;
        __syncthreads();
        lds[t] += add;
        __syncthreads();
    }
    if (t < nb) {
        int ex = lds[t] - v;
        bcursor[t] = ex;
        bbase[t] = ex;
    }
    if (t == 0) bbase[nb] = n_edges;
}

// ============================================================================
// Stage 3a: bin edges by bucket (= row>>8); LDS hist -> one global atomic
// per (block,bucket) -> contiguous runs per bucket. R11-proven.
// ============================================================================
__global__ __launch_bounds__(256) void bin_kernel(
    const int* __restrict__ erow, const int* __restrict__ ecol,
    const float* __restrict__ ew, int* __restrict__ bcursor,
    uint2* __restrict__ btmp, int n_edges)
{
    __shared__ int lcnt[256];
    const int t = threadIdx.x;
    const int base = blockIdx.x * 4096;
    lcnt[t] = 0;
    __syncthreads();

    unsigned rc[16];
    float    wv[16];
#pragma unroll
    for (int i = 0; i < 16; ++i) {
        int idx = base + i * 256 + t;
        if (idx < n_edges) {
            int r = erow[idx];
            rc[i] = ((unsigned)r << 16) | (unsigned)ecol[idx];
            wv[i] = ew[idx];
            atomicAdd(&lcnt[r >> 8], 1);
        } else {
            rc[i] = 0xFFFFFFFFu;
        }
    }
    __syncthreads();
    int c = lcnt[t];
    int gbase = (c > 0) ? atomicAdd(&bcursor[t], c) : 0;
    lcnt[t] = gbase;
    __syncthreads();
#pragma unroll
    for (int i = 0; i < 16; ++i) {
        if (rc[i] != 0xFFFFFFFFu) {
            int b = rc[i] >> 24;
            int pos = atomicAdd(&lcnt[b], 1);
            uint2 p;
            p.x = rc[i];
            p.y = __float_as_uint(wv[i]);
            btmp[pos] = p;
        }
    }
}

// ============================================================================
// Stage 3b: per-bucket CSR build + final scatter (R11-proven).
// ============================================================================
__global__ __launch_bounds__(256) void sort_kernel(
    const uint2* __restrict__ btmp, const int* __restrict__ bbase,
    int* __restrict__ cnt, int* __restrict__ beg,
    unsigned* __restrict__ sedge4, int n)
{
    __shared__ int lscan[256];
    __shared__ int lofs[256];
    const int b = blockIdx.x;
    const int t = threadIdx.x;
    const int lo = bbase[b];
    const int hi = bbase[b + 1];

    lscan[t] = 0;
    __syncthreads();
    for (int i = lo + t; i < hi; i += 256) {
        int rl = (btmp[i].x >> 16) & 255;
        atomicAdd(&lscan[rl], 1);
    }
    __syncthreads();
    int v = lscan[t];
    __syncthreads();
#pragma unroll
    for (int off = 1; off < 256; off <<= 1) {
        int add = (t >= off) ? lscan[t - off] : 0;
        __syncthreads();
        lscan[t] += add;
        __syncthreads();
    }
    int ex = lscan[t] - v;
    lofs[t] = ex;
    int row = b * 256 + t;
    if (row < n) {
        cnt[row] = v;
        beg[row] = lo + ex;
    }
    __syncthreads();
    for (int i = lo + t; i < hi; i += 256) {
        uint2 p = btmp[i];
        int rl = (p.x >> 16) & 255;
        int pos = atomicAdd(&lofs[rl], 1);
        float w = __uint_as_float(p.y);
        sedge4[lo + pos] = (p.x & 0xFFFFu) | ((unsigned)f_to_h16(w) << 16);
    }
}

// ============================================================================
// Stage 4: CSR SpMM, 4B records, fp16 gather. Predicated full-MLP groups of
// 16 (16 independent gathers in flight; record array has zeroed slack).
// ============================================================================
__global__ __launch_bounds__(256) void spmm4_kernel(
    const __half2* __restrict__ inph, const float* __restrict__ h0,
    const int* __restrict__ begp, const int* __restrict__ cnt,
    const unsigned* __restrict__ sedge4,
    const float* __restrict__ alpha_p, __half2* __restrict__ s16out, int n)
{
    int lane = threadIdx.x & 63;
    int row  = blockIdx.x * 4 + (threadIdx.x >> 6);
    if (row >= n) return;

    int deg = cnt[row];
    int beg = begp[row];

    float2 a0 = {0.f, 0.f}, a1 = {0.f, 0.f}, a2 = {0.f, 0.f}, a3 = {0.f, 0.f};
    for (int e = 0; e < deg; e += 16) {
        unsigned r[16];
#pragma unroll
        for (int i = 0; i < 16; ++i) r[i] = sedge4[beg + e + i];
        __half2 v[16];
#pragma unroll
        for (int i = 0; i < 16; ++i)
            v[i] = inph[(size_t)(r[i] & 0xFFFFu) * 64 + lane];
#pragma unroll
        for (int i = 0; i < 16; ++i) {
            float w = h16_to_f((e + i < deg) ? (unsigned short)(r[i] >> 16)
                                             : (unsigned short)0);
            float2 f = __half22float2(v[i]);
            if ((i & 3) == 0) { a0.x = fmaf(w, f.x, a0.x); a0.y = fmaf(w, f.y, a0.y); }
            if ((i & 3) == 1) { a1.x = fmaf(w, f.x, a1.x); a1.y = fmaf(w, f.y, a1.y); }
            if ((i & 3) == 2) { a2.x = fmaf(w, f.x, a2.x); a2.y = fmaf(w, f.y, a2.y); }
            if ((i & 3) == 3) { a3.x = fmaf(w, f.x, a3.x); a3.y = fmaf(w, f.y, a3.y); }
        }
    }
    float2 acc;
    acc.x = (a0.x + a1.x) + (a2.x + a3.x);
    acc.y = (a0.y + a1.y) + (a2.y + a3.y);

    const float alpha = alpha_p[0];
    const float oma   = 1.0f - alpha;
    float2 h = reinterpret_cast<const float2*>(h0)[(size_t)row * 64 + lane];
    float sx = fmaf(oma, acc.x, alpha * h.x);
    float sy = fmaf(oma, acc.y, alpha * h.y);
    s16out[(size_t)row * 64 + lane] = __floats2half2_rn(sx, sy);
}

// ============================================================================
// Stage 5: MFMA GEMM + blend + residual (R6-verified layout).
// ============================================================================
__global__ __launch_bounds__(256) void gemm_mfma_kernel(
    const __half* __restrict__ s16, const __half* __restrict__ wt16,
    const float* __restrict__ input, float* __restrict__ out,
    const float* __restrict__ lamda_p, const int* __restrict__ l_p,
    int n_rows)
{
    const int wave = threadIdx.x >> 6;
    const int lane = threadIdx.x & 63;
    const int row0 = (blockIdx.x * 4 + wave) * 16;
    if (row0 >= n_rows) return;

    const int mr = lane & 15;
    const int kg = lane >> 4;

    const _Float16* sp = reinterpret_cast<const _Float16*>(s16);
    const _Float16* wp = reinterpret_cast<const _Float16*>(wt16);

    float4_t acc[8];
#pragma unroll
    for (int nt = 0; nt < 8; ++nt) acc[nt] = (float4_t){0.f, 0.f, 0.f, 0.f};

#pragma unroll
    for (int ks = 0; ks < 4; ++ks) {
        const int kofs = ks * 32 + kg * 8;
        half8_t a = *reinterpret_cast<const half8_t*>(
            sp + (size_t)(row0 + mr) * D_FEAT + kofs);
#pragma unroll
        for (int nt = 0; nt < 8; ++nt) {
            half8_t b = *reinterpret_cast<const half8_t*>(
                wp + (size_t)(nt * 16 + mr) * D_FEAT + kofs);
            acc[nt] = __builtin_amdgcn_mfma_f32_16x16x32_f16(a, b, acc[nt], 0, 0, 0);
        }
    }

    const float lamda = lamda_p[0];
    const float theta = fminf(1.0f, logf(lamda / (float)l_p[0] + 1.0f));
    const float om_theta = 1.0f - theta;

#pragma unroll
    for (int nt = 0; nt < 8; ++nt) {
#pragma unroll
        for (int r = 0; r < 4; ++r) {
            const int row = row0 + kg * 4 + r;
            const int col = nt * 16 + mr;
            const size_t idx = (size_t)row * D_FEAT + col;
            const float s = (float)sp[idx];
            out[idx] = fmaf(theta, acc[nt][r], fmaf(om_theta, s, input[idx]));
        }
    }
}

// ======================= fallback paths (B/C, from R5) ======================
__global__ __launch_bounds__(256) void hist_kernel(
    const int* __restrict__ erow, int* __restrict__ cnt, int n_edges)
{
    int e = blockIdx.x * 256 + threadIdx.x;
    if (e < n_edges) atomicAdd(&cnt[erow[e]], 1);
}

__global__ __launch_bounds__(256) void prep_noW_kernel(
    const float* __restrict__ input, unsigned* __restrict__ inph_u2,
    const int* __restrict__ erow, int* __restrict__ cnt,
    int nconv4, int n_edges)
{
    int tid = blockIdx.x * 256 + threadIdx.x;
    if (tid < nconv4) {
        float4 v = reinterpret_cast<const float4*>(input)[tid];
        __half2 a = __floats2half2_rn(v.x, v.y);
        __half2 b = __floats2half2_rn(v.z, v.w);
        uint2 p;
        p.x = *reinterpret_cast<unsigned*>(&a);
        p.y = *reinterpret_cast<unsigned*>(&b);
        reinterpret_cast<uint2*>(inph_u2)[tid] = p;
    } else {
        int e = tid - nconv4;
        if (e < n_edges) atomicAdd(&cnt[erow[e]], 1);
    }
}

__global__ __launch_bounds__(256) void partial_kernel(
    const int* __restrict__ cnt, int* __restrict__ partial, int n)
{
    __shared__ int lds[4];
    int i = blockIdx.x * 256 + threadIdx.x;
    int v = (i < n) ? cnt[i] : 0;
#pragma unroll
    for (int off = 32; off > 0; off >>= 1) v += __shfl_down(v, off, 64);
    if ((threadIdx.x & 63) == 0) lds[threadIdx.x >> 6] = v;
    __syncthreads();
    if (threadIdx.x == 0)
        partial[blockIdx.x] = lds[0] + lds[1] + lds[2] + lds[3];
}

__global__ __launch_bounds__(256) void scan_partial_kernel(
    int* __restrict__ partial, int nb)
{
    __shared__ int lds[256];
    int t = threadIdx.x;
    int v = (t < nb) ? partial[t] : 0;
    lds[t] = v;
    __syncthreads();
#pragma unroll
    for (int off = 1; off < 256; off <<= 1) {
        int add = (t >= off) ? lds[t - off] : 0;
        __syncthreads();
        lds[t] += add;
        __syncthreads();
    }
    if (t < nb) partial[t] = lds[t] - v;
}

__global__ __launch_bounds__(256) void scan_final_kernel(
    const int* __restrict__ cnt, const int* __restrict__ partial,
    int* __restrict__ cursor, int n)
{
    __shared__ int lds[256];
    int t = threadIdx.x;
    int i = blockIdx.x * 256 + t;
    int v = (i < n) ? cnt[i] : 0;
    lds[t] = v;
    __syncthreads();
#pragma unroll
    for (int off = 1; off < 256; off <<= 1) {
        int add = (t >= off) ? lds[t - off] : 0;
        __syncthreads();
        lds[t] += add;
        __syncthreads();
    }
    if (i < n) cursor[i] = lds[t] - v + partial[blockIdx.x];
}

__global__ __launch_bounds__(256) void edge_scatter_kernel(
    const int* __restrict__ erow, const int* __restrict__ ecol,
    const float* __restrict__ ew, int* __restrict__ cursor,
    uint2* __restrict__ sedge, int n_edges)
{
    int e = blockIdx.x * 256 + threadIdx.x;
    if (e >= n_edges) return;
    int r = erow[e];
    int pos = atomicAdd(&cursor[r], 1);
    uint2 p;
    p.x = (unsigned)ecol[e];
    p.y = __float_as_uint(ew[e]);
    sedge[pos] = p;
}

__global__ __launch_bounds__(256) void spmm_fp16_kernel(
    const __half2* __restrict__ inph, const float* __restrict__ h0,
    const int* __restrict__ cursor, const int* __restrict__ cnt,
    const uint2* __restrict__ sedge,
    const float* __restrict__ alpha_p, float* __restrict__ outp, int n)
{
    int lane = threadIdx.x & 63;
    int row  = blockIdx.x * 4 + (threadIdx.x >> 6);
    if (row >= n) return;
    int deg = cnt[row];
    int beg = cursor[row] - deg;
    float2 accA = make_float2(0.f, 0.f), accB = make_float2(0.f, 0.f);
    int e = 0;
    for (; e + 2 <= deg; e += 2) {
        uint2 e0 = sedge[beg + e], e1 = sedge[beg + e + 1];
        __half2 v0 = inph[(size_t)e0.x * 64 + lane];
        __half2 v1 = inph[(size_t)e1.x * 64 + lane];
        float w0 = __uint_as_float(e0.y), w1 = __uint_as_float(e1.y);
        float2 f0 = __half22float2(v0), f1 = __half22float2(v1);
        accA.x = fmaf(w0, f0.x, accA.x); accA.y = fmaf(w0, f0.y, accA.y);
        accB.x = fmaf(w1, f1.x, accB.x); accB.y = fmaf(w1, f1.y, accB.y);
    }
    if (e < deg) {
        uint2 e0 = sedge[beg + e];
        __half2 v0 = inph[(size_t)e0.x * 64 + lane];
        float w0 = __uint_as_float(e0.y);
        float2 f0 = __half22float2(v0);
        accA.x = fmaf(w0, f0.x, accA.x); accA.y = fmaf(w0, f0.y, accA.y);
    }
    float2 acc; acc.x = accA.x + accB.x; acc.y = accA.y + accB.y;
    const float alpha = alpha_p[0], oma = 1.0f - alpha;
    float2 h = reinterpret_cast<const float2*>(h0)[(size_t)row * 64 + lane];
    float2 s;
    s.x = fmaf(oma, acc.x, alpha * h.x);
    s.y = fmaf(oma, acc.y, alpha * h.y);
    reinterpret_cast<float2*>(outp)[(size_t)row * 64 + lane] = s;
}

__global__ __launch_bounds__(256) void spmm_fp32_kernel(
    const float* __restrict__ input, const float* __restrict__ h0,
    const int* __restrict__ cursor, const int* __restrict__ cnt,
    const uint2* __restrict__ sedge,
    const float* __restrict__ alpha_p, float* __restrict__ outp, int n)
{
    int lane = threadIdx.x & 63;
    int row  = blockIdx.x * 4 + (threadIdx.x >> 6);
    if (row >= n) return;
    int deg = cnt[row];
    int beg = cursor[row] - deg;
    const float2* in2 = reinterpret_cast<const float2*>(input);
    float2 acc = make_float2(0.f, 0.f);
    for (int e = 0; e < deg; ++e) {
        uint2 ed = sedge[beg + e];
        float w = __uint_as_float(ed.y);
        float2 v = in2[(size_t)ed.x * 64 + lane];
        acc.x = fmaf(w, v.x, acc.x);
        acc.y = fmaf(w, v.y, acc.y);
    }
    const float alpha = alpha_p[0], oma = 1.0f - alpha;
    float2 h = reinterpret_cast<const float2*>(h0)[(size_t)row * 64 + lane];
    float2 s;
    s.x = fmaf(oma, acc.x, alpha * h.x);
    s.y = fmaf(oma, acc.y, alpha * h.y);
    reinterpret_cast<float2*>(outp)[(size_t)row * 64 + lane] = s;
}

__global__ __launch_bounds__(256) void fused_kernel(
    float* __restrict__ io, const float* __restrict__ input,
    const float* __restrict__ W,
    const float* __restrict__ lamda_p, const int* __restrict__ l_p,
    int n_rows)
{
    __shared__ float s_lds[2][D_FEAT];
    const int j = threadIdx.x & 127;
    const int r = threadIdx.x >> 7;
    float wcol[D_FEAT];
#pragma unroll
    for (int k = 0; k < D_FEAT; ++k) wcol[k] = W[k * D_FEAT + j];
    const float lamda = lamda_p[0];
    const float theta = fminf(1.0f, logf(lamda / (float)l_p[0] + 1.0f));
    const float om_theta = 1.0f - theta;
    for (int row0 = blockIdx.x * 2; row0 < n_rows; row0 += gridDim.x * 2) {
        const int row = row0 + r;
        const bool active = row < n_rows;
        float sj = 0.0f;
        if (active) {
            sj = io[(size_t)row * D_FEAT + j];
            s_lds[r][j] = sj;
        }
        __syncthreads();
        if (active) {
            float dot = 0.0f;
            const float4* s4 = reinterpret_cast<const float4*>(s_lds[r]);
#pragma unroll
            for (int k4 = 0; k4 < D_FEAT / 4; ++k4) {
                const float4 sv = s4[k4];
                dot = fmaf(sv.x, wcol[4 * k4 + 0], dot);
                dot = fmaf(sv.y, wcol[4 * k4 + 1], dot);
                dot = fmaf(sv.z, wcol[4 * k4 + 2], dot);
                dot = fmaf(sv.w, wcol[4 * k4 + 3], dot);
            }
            const size_t base = (size_t)row * D_FEAT + j;
            io[base] = fmaf(theta, dot, om_theta * sj) + input[base];
        }
        __syncthreads();
    }
}

extern "C" void kernel_launch(void* const* d_in, const int* in_sizes, int n_in,
                              void* d_out, int out_size, void* d_ws, size_t ws_size,
                              hipStream_t stream)
{
    const float* input = (const float*)d_in[0];
    const float* h0    = (const float*)d_in[1];
    const float* W     = (const float*)d_in[2];
    const int*   erow  = (const int*)d_in[3];
    const int*   ecol  = (const int*)d_in[4];
    const float* ew    = (const float*)d_in[5];
    const float* lamda = (const float*)d_in[6];
    const float* alpha = (const float*)d_in[7];
    const int*   l_p   = (const int*)d_in[8];
    float* out = (float*)d_out;

    const int n_nodes = in_sizes[0] / D_FEAT;   // 50000
    const int n_edges = in_sizes[3];            // 800000
    const int nb = (n_nodes + 255) / 256;       // 196
    const int nconv4 = n_nodes * D_FEAT / 4;
    const int histBlocks = (n_edges + 4095) / 4096;

    // ---- new-path workspace layout ----
    // cnt:N | beg:N | bucket_cnt:256 | bcursor:257 | bbase:257 |
    // sedge4:(E+16) u32 | inph:N*128 fp16 | union[btmp E uint2 / s16] | wt16
    char* p = (char*)d_ws;
    auto align16 = [](char* q) {
        return (char*)(((uintptr_t)q + 15) & ~(uintptr_t)15);
    };
    int* cnt      = (int*)p;                    p += (size_t)n_nodes * 4;
    int* beg      = (int*)p;                    p += (size_t)n_nodes * 4;
    int* bucket_cnt = (int*)p;                  p += 256 * 4;
    int* bcursor  = (int*)p;                    p += 257 * 4;
    int* bbase    = (int*)p;                    p += 257 * 4;
    p = align16(p);
    unsigned* sedge4 = (unsigned*)p;            p += ((size_t)n_edges + 16) * 4;
    p = align16(p);
    unsigned* inph  = (unsigned*)p;             p += (size_t)n_nodes * D_FEAT * 2;
    p = align16(p);
    char* unionp = p;
    uint2*  btmp = (uint2*)unionp;
    __half* s16  = (__half*)unionp;
    size_t union_bytes = (size_t)n_nodes * D_FEAT * 2;
    if ((size_t)n_edges * 8 > union_bytes) union_bytes = (size_t)n_edges * 8;
    p += union_bytes;
    p = align16(p);
    __half* wt16 = (__half*)p;                  p += (size_t)D_FEAT * D_FEAT * 2;
    const size_t need_new = (size_t)(p - (char*)d_ws);

    const bool use_new = (ws_size >= need_new) && (n_nodes < 65536) && (nb <= 256);

    if (use_new) {
        const int convBlocks = (nconv4 + 255) / 256;
        const int wBlocks = (D_FEAT * D_FEAT + 255) / 256;
        const int totalBlocks = convBlocks + wBlocks + 1 + histBlocks;

        hipMemsetAsync(bucket_cnt, 0, 256 * sizeof(int), stream);
        prep_kernel<<<totalBlocks, 256, 0, stream>>>(
            input, inph, W, wt16, sedge4 + n_edges, erow, bucket_cnt,
            nconv4, n_edges, convBlocks, wBlocks);
        bucket_scan_kernel<<<1, 256, 0, stream>>>(
            bucket_cnt, bcursor, bbase, nb, n_edges);
        bin_kernel<<<histBlocks, 256, 0, stream>>>(
            erow, ecol, ew, bcursor, btmp, n_edges);
        sort_kernel<<<nb, 256, 0, stream>>>(
            btmp, bbase, cnt, beg, sedge4, n_nodes);
        spmm4_kernel<<<(n_nodes + 3) / 4, 256, 0, stream>>>(
            (const __half2*)inph, h0, beg, cnt, sedge4, alpha,
            (__half2*)s16, n_nodes);
        const int ntiles = (n_nodes + 15) / 16;
        gemm_mfma_kernel<<<(ntiles + 3) / 4, 256, 0, stream>>>(
            s16, wt16, input, out, lamda, l_p, n_nodes);
        return;
    }

    // ---------------- fallback (R5 layout & paths) ----------------
    int*   fcnt     = (int*)d_ws;
    int*   fcursor  = fcnt + n_nodes;
    int*   fpartial = fcursor + n_nodes;
    uint2* fsedge   = (uint2*)(fpartial + 256);
    unsigned* finph = (unsigned*)(fsedge + n_edges);

    const size_t need_base = (size_t)(2 * n_nodes + 256) * 4 + (size_t)n_edges * 8;
    const size_t need_fp16 = need_base + (size_t)n_nodes * D_FEAT * 2;
    const bool use_fp16 = ws_size >= need_fp16;

    hipMemsetAsync(fcnt, 0, (size_t)n_nodes * sizeof(int), stream);

    if (use_fp16) {
        int total = nconv4 + n_edges;
        prep_noW_kernel<<<(total + 255) / 256, 256, 0, stream>>>(
            input, finph, erow, fcnt, nconv4, n_edges);
    } else {
        hist_kernel<<<(n_edges + 255) / 256, 256, 0, stream>>>(erow, fcnt, n_edges);
    }
    partial_kernel<<<nb, 256, 0, stream>>>(fcnt, fpartial, n_nodes);
    scan_partial_kernel<<<1, 256, 0, stream>>>(fpartial, nb);
    scan_final_kernel<<<nb, 256, 0, stream>>>(fcnt, fpartial, fcursor, n_nodes);
    edge_scatter_kernel<<<(n_edges + 255) / 256, 256, 0, stream>>>(
        erow, ecol, ew, fcursor, fsedge, n_edges);
    if (use_fp16) {
        spmm_fp16_kernel<<<(n_nodes + 3) / 4, 256, 0, stream>>>(
            (const __half2*)finph, h0, fcursor, fcnt, fsedge, alpha, out, n_nodes);
    } else {
        spmm_fp32_kernel<<<(n_nodes + 3) / 4, 256, 0, stream>>>(
            input, h0, fcursor, fcnt, fsedge, alpha, out, n_nodes);
    }
    fused_kernel<<<2048, 256, 0, stream>>>(out, input, W, lamda, l_p, n_nodes);
}